// Round 6
// baseline (285.615 us; speedup 1.0000x reference)
//
#include <hip/hip_runtime.h>

#define N_NODES 100000
#define N_EDGES 1600000
#define D 128
#define RPB 64                       // node rows per bucket
#define NBUCKET 1563                 // ceil(N_NODES / RPB)
#define NBLK 196                     // partition blocks
#define EPB 8192                     // edges per partition block
#define M_HIST (NBUCKET * NBLK)      // 306348
#define NPART ((M_HIST + 255) / 256) // 1197
#define AGG_CAP 2048                 // max edges per bucket (mean 1024, +32 sigma)
#define XCB 3125                     // xconv blocks (3.2M float4 / 1024)

constexpr float LN_EPS   = 1e-5f;
constexpr float MEAN_EPS = 1e-8f;

typedef __attribute__((ext_vector_type(8))) short bf16x8;
typedef __attribute__((ext_vector_type(4))) float f32x4;
typedef __attribute__((ext_vector_type(2))) float f32x2;

__device__ inline unsigned short f2bf(float f) {
  union { float f; unsigned u; } v; v.f = f;
  return (unsigned short)((v.u + 0x7FFFu + ((v.u >> 16) & 1u)) >> 16);
}

// ---------------------------------------------------------------------------
// Fused prep: blocks [0,NBLK) = partA histogram; [NBLK,NBLK+XCB) = x->bf16+fp8;
// last 16 blocks = W concat->bf16 + bias sum. Saves 2 launches.
// ---------------------------------------------------------------------------
__global__ __launch_bounds__(256) void prep_kernel(
    const float* __restrict__ x, const int* __restrict__ ei,
    const float* __restrict__ Wself, const float* __restrict__ Wagg,
    const float* __restrict__ bself, const float* __restrict__ bagg,
    unsigned short* __restrict__ xb, unsigned* __restrict__ xf8,
    unsigned short* __restrict__ wcat, float* __restrict__ bsum,
    int* __restrict__ hist) {
  __shared__ int cnt_s[NBUCKET];   // used by partA blocks only
  const int bid = blockIdx.x;
  const int t = threadIdx.x;

  if (bid < NBLK) {
    // ---- partA: per-block histogram over buckets
    for (int b = t; b < NBUCKET; b += 256) cnt_s[b] = 0;
    __syncthreads();
    const int base4 = bid * (EPB / 4);
    const int lim4 = N_EDGES / 4;
#pragma unroll
    for (int k = 0; k < EPB / 1024; ++k) {
      int i4 = base4 + k * 256 + t;
      if (i4 < lim4) {
        int4 r = ((const int4*)ei)[i4];
        atomicAdd(&cnt_s[r.x >> 6], 1);
        atomicAdd(&cnt_s[r.y >> 6], 1);
        atomicAdd(&cnt_s[r.z >> 6], 1);
        atomicAdd(&cnt_s[r.w >> 6], 1);
      }
    }
    __syncthreads();
    for (int b = t; b < NBUCKET; b += 256)
      hist[b * NBLK + bid] = cnt_s[b];
  } else if (bid < NBLK + XCB) {
    // ---- xconv: 4 float4 per thread -> bf16x4 + fp8x4(packed uint)
    const int base = (bid - NBLK) * 1024;
#pragma unroll
    for (int k = 0; k < 4; ++k) {
      int i4 = base + k * 256 + t;   // < 3.2M always (XCB*1024 == 3.2M)
      float4 v = ((const float4*)x)[i4];
      ushort4 o;
      o.x = f2bf(v.x); o.y = f2bf(v.y); o.z = f2bf(v.z); o.w = f2bf(v.w);
      ((ushort4*)xb)[i4] = o;
      int r = 0;
      r = __builtin_amdgcn_cvt_pk_fp8_f32(v.x, v.y, r, false);
      r = __builtin_amdgcn_cvt_pk_fp8_f32(v.z, v.w, r, true);
      xf8[i4] = (unsigned)r;
    }
  } else {
    // ---- wconv: 16 blocks cover 128x256 weights
    const int blk = bid - NBLK - XCB;
#pragma unroll
    for (int k = 0; k < 8; ++k) {
      int idx = blk * 2048 + k * 256 + t;
      int o = idx >> 8, kc = idx & 255;
      float v = (kc < 128) ? Wself[o * 128 + kc] : Wagg[o * 128 + (kc - 128)];
      wcat[o * 256 + kc] = f2bf(v);
    }
    if (blk == 0 && t < 128) bsum[t] = bself[t] + bagg[t];
  }
}

// ---------------------------------------------------------------------------
// Exclusive scan over M_HIST ints (3-kernel structure, proven R2-R5)
// ---------------------------------------------------------------------------
__global__ __launch_bounds__(256) void scan_partials(const int* __restrict__ in,
                                                     int* __restrict__ partials) {
  __shared__ int s[256];
  int i = blockIdx.x * 256 + threadIdx.x;
  s[threadIdx.x] = (i < M_HIST) ? in[i] : 0;
  __syncthreads();
  for (int off = 128; off > 0; off >>= 1) {
    if (threadIdx.x < off) s[threadIdx.x] += s[threadIdx.x + off];
    __syncthreads();
  }
  if (threadIdx.x == 0) partials[blockIdx.x] = s[0];
}

__global__ __launch_bounds__(256) void scan_block(int* __restrict__ partials) {
  __shared__ int s[256];
  __shared__ int carry;
  if (threadIdx.x == 0) carry = 0;
  __syncthreads();
  for (int base = 0; base < NPART; base += 256) {
    int i = base + threadIdx.x;
    int v = (i < NPART) ? partials[i] : 0;
    s[threadIdx.x] = v;
    __syncthreads();
    for (int off = 1; off < 256; off <<= 1) {
      int t = (threadIdx.x >= off) ? s[threadIdx.x - off] : 0;
      __syncthreads();
      s[threadIdx.x] += t;
      __syncthreads();
    }
    int excl = s[threadIdx.x] - v + carry;
    if (i < NPART) partials[i] = excl;
    __syncthreads();
    if (threadIdx.x == 0) carry += s[255];
    __syncthreads();
  }
}

__global__ __launch_bounds__(256) void scan_final(const int* __restrict__ in,
                                                  const int* __restrict__ partials,
                                                  int* __restrict__ scanned) {
  __shared__ int s[256];
  int i = blockIdx.x * 256 + threadIdx.x;
  int v = (i < M_HIST) ? in[i] : 0;
  s[threadIdx.x] = v;
  __syncthreads();
  for (int off = 1; off < 256; off <<= 1) {
    int t = (threadIdx.x >= off) ? s[threadIdx.x - off] : 0;
    __syncthreads();
    s[threadIdx.x] += t;
    __syncthreads();
  }
  if (i < M_HIST) scanned[i] = s[threadIdx.x] - v + partials[blockIdx.x];
}

// ---------------------------------------------------------------------------
// Pass B: place edges into dense per-(block,bucket) ranges. LDS cursors only.
// ---------------------------------------------------------------------------
__global__ __launch_bounds__(256) void partB_scatter(const int* __restrict__ ei,
                                                     const int* __restrict__ scanned,
                                                     unsigned* __restrict__ edges_part) {
  __shared__ int cur_s[NBUCKET];
  const int t = threadIdx.x;
  for (int b = t; b < NBUCKET; b += 256)
    cur_s[b] = scanned[b * NBLK + blockIdx.x];
  __syncthreads();
  const int base4 = blockIdx.x * (EPB / 4);
  const int lim4 = N_EDGES / 4;
#pragma unroll
  for (int k = 0; k < EPB / 1024; ++k) {
    int i4 = base4 + k * 256 + t;
    if (i4 < lim4) {
      int4 r = ((const int4*)ei)[i4];
      int4 c = ((const int4*)(ei + N_EDGES))[i4];
      int p0 = atomicAdd(&cur_s[r.x >> 6], 1);
      edges_part[p0] = ((unsigned)(r.x & 63) << 17) | (unsigned)c.x;
      int p1 = atomicAdd(&cur_s[r.y >> 6], 1);
      edges_part[p1] = ((unsigned)(r.y & 63) << 17) | (unsigned)c.y;
      int p2 = atomicAdd(&cur_s[r.z >> 6], 1);
      edges_part[p2] = ((unsigned)(r.z & 63) << 17) | (unsigned)c.z;
      int p3 = atomicAdd(&cur_s[r.w >> 6], 1);
      edges_part[p3] = ((unsigned)(r.w & 63) << 17) | (unsigned)c.w;
    }
  }
}

// ---------------------------------------------------------------------------
// Local counting sort (LDS) + pull-mode mean aggregation over FP8 x.
// 8 lane-groups x 8 lanes x uint4 (16 fp8) => 8 edges in flight per wave.
// Mean written bf16 into the first 256B of the node's d_out row.
// ---------------------------------------------------------------------------
__global__ __launch_bounds__(256) void aggregate_bucket(
    const unsigned* __restrict__ xf8, const int* __restrict__ scanned,
    const unsigned* __restrict__ edges_part, float* out) {
  __shared__ int cnt_s[RPB];
  __shared__ int off_s[RPB];
  __shared__ int cur_s[RPB];
  __shared__ int col_s[AGG_CAP];

  const int b = blockIdx.x;
  const int t = threadIdx.x;
  const int beg = scanned[b * NBLK];
  const int end = (b == NBUCKET - 1) ? N_EDGES : scanned[(b + 1) * NBLK];
  int n = end - beg; if (n > AGG_CAP) n = AGG_CAP;

  if (t < RPB) cnt_s[t] = 0;
  __syncthreads();
  for (int i = t; i < n; i += 256)
    atomicAdd(&cnt_s[edges_part[beg + i] >> 17], 1);
  __syncthreads();

  if (t < RPB) off_s[t] = cnt_s[t];
  __syncthreads();
  for (int off = 1; off < RPB; off <<= 1) {
    int u = 0;
    if (t < RPB && t >= off) u = off_s[t - off];
    __syncthreads();
    if (t < RPB) off_s[t] += u;
    __syncthreads();
  }
  int excl = 0;
  if (t < RPB) excl = off_s[t] - cnt_s[t];
  __syncthreads();
  if (t < RPB) { off_s[t] = excl; cur_s[t] = excl; }
  __syncthreads();

  for (int i = t; i < n; i += 256) {   // edges_part re-read: L2-warm
    unsigned e = edges_part[beg + i];
    int pos = atomicAdd(&cur_s[e >> 17], 1);
    col_s[pos] = (int)(e & 0x1FFFFu);
  }
  __syncthreads();

  const int w = t >> 6, lane = t & 63;
  const int grp = lane >> 3, l = lane & 7;   // 8 groups x 8 lanes
  const int nodebase = b << 6;
  for (int lrow = w; lrow < RPB; lrow += 4) {
    int node = nodebase + lrow;
    if (node >= N_NODES) break;
    int rbeg = off_s[lrow];
    int deg = cnt_s[lrow];
    float acc[16];
#pragma unroll
    for (int k = 0; k < 16; ++k) acc[k] = 0.f;
    for (int j0 = 0; j0 < deg; j0 += 16) {
      int j1 = j0 + grp, j2 = j0 + 8 + grp;
      uint4 p1, p2;
      bool v1 = j1 < deg, v2 = j2 < deg;
      if (v1) p1 = ((const uint4*)(xf8 + (size_t)col_s[rbeg + j1] * 32))[l];
      if (v2) p2 = ((const uint4*)(xf8 + (size_t)col_s[rbeg + j2] * 32))[l];
      if (v1) {
        f32x2 f;
        f = __builtin_amdgcn_cvt_pk_f32_fp8(p1.x, false); acc[0] += f[0];  acc[1] += f[1];
        f = __builtin_amdgcn_cvt_pk_f32_fp8(p1.x, true);  acc[2] += f[0];  acc[3] += f[1];
        f = __builtin_amdgcn_cvt_pk_f32_fp8(p1.y, false); acc[4] += f[0];  acc[5] += f[1];
        f = __builtin_amdgcn_cvt_pk_f32_fp8(p1.y, true);  acc[6] += f[0];  acc[7] += f[1];
        f = __builtin_amdgcn_cvt_pk_f32_fp8(p1.z, false); acc[8] += f[0];  acc[9] += f[1];
        f = __builtin_amdgcn_cvt_pk_f32_fp8(p1.z, true);  acc[10] += f[0]; acc[11] += f[1];
        f = __builtin_amdgcn_cvt_pk_f32_fp8(p1.w, false); acc[12] += f[0]; acc[13] += f[1];
        f = __builtin_amdgcn_cvt_pk_f32_fp8(p1.w, true);  acc[14] += f[0]; acc[15] += f[1];
      }
      if (v2) {
        f32x2 f;
        f = __builtin_amdgcn_cvt_pk_f32_fp8(p2.x, false); acc[0] += f[0];  acc[1] += f[1];
        f = __builtin_amdgcn_cvt_pk_f32_fp8(p2.x, true);  acc[2] += f[0];  acc[3] += f[1];
        f = __builtin_amdgcn_cvt_pk_f32_fp8(p2.y, false); acc[4] += f[0];  acc[5] += f[1];
        f = __builtin_amdgcn_cvt_pk_f32_fp8(p2.y, true);  acc[6] += f[0];  acc[7] += f[1];
        f = __builtin_amdgcn_cvt_pk_f32_fp8(p2.z, false); acc[8] += f[0];  acc[9] += f[1];
        f = __builtin_amdgcn_cvt_pk_f32_fp8(p2.z, true);  acc[10] += f[0]; acc[11] += f[1];
        f = __builtin_amdgcn_cvt_pk_f32_fp8(p2.w, false); acc[12] += f[0]; acc[13] += f[1];
        f = __builtin_amdgcn_cvt_pk_f32_fp8(p2.w, true);  acc[14] += f[0]; acc[15] += f[1];
      }
    }
#pragma unroll
    for (int k = 0; k < 16; ++k) {
      acc[k] += __shfl_xor(acc[k], 8, 64);
      acc[k] += __shfl_xor(acc[k], 16, 64);
      acc[k] += __shfl_xor(acc[k], 32, 64);
    }
    if (grp == 0) {
      float inv = 1.0f / ((float)deg + MEAN_EPS);
      unsigned o[8];
#pragma unroll
      for (int k = 0; k < 8; ++k)
        o[k] = (unsigned)f2bf(acc[2 * k] * inv) |
               ((unsigned)f2bf(acc[2 * k + 1] * inv) << 16);
      uint4* dst = (uint4*)(out + (size_t)node * D);   // lane l: bytes [32l,32l+32)
      dst[2 * l]     = make_uint4(o[0], o[1], o[2], o[3]);
      dst[2 * l + 1] = make_uint4(o[4], o[5], o[6], o[7]);
    }
  }
}

// ---------------------------------------------------------------------------
// MFMA GEMM: C[100000x128] = [x_bf16 | mean_bf16] (K=256) @ Wcat^T  + LN
// (unchanged from R3-R5)
// ---------------------------------------------------------------------------
__global__ __launch_bounds__(512) void gemm_mfma_ln(
    const unsigned short* __restrict__ xb, const float* out_mean,
    const unsigned short* __restrict__ wcat, const float* __restrict__ bsum,
    const float* __restrict__ gamma, const float* __restrict__ beta,
    float* out) {
  __shared__ unsigned short As[128 * 264];
  __shared__ unsigned short Bs[128 * 264];
  __shared__ float bias_s[128];

  const int t = threadIdx.x;
  const int w = t >> 6, lane = t & 63;
  const int q = lane >> 4, s = lane & 15;
  const int base = blockIdx.x * 128;

  if (t < 128) bias_s[t] = bsum[t];

#pragma unroll
  for (int r = 0; r < 8; ++r) {
    int f = r * 512 + t;
    int row = f >> 5, c = f & 31;
    uint4 v = *(const uint4*)(wcat + row * 256 + c * 8);
    *(uint4*)(Bs + row * 264 + c * 8) = v;
  }
#pragma unroll
  for (int r = 0; r < 8; ++r) {
    int f = r * 512 + t;
    int row = f >> 5, c = f & 31;
    int node = base + row;
    uint4 v = make_uint4(0, 0, 0, 0);
    if (node < N_NODES) {
      const unsigned short* src = (c < 16)
          ? xb + (size_t)node * 128 + c * 8
          : (const unsigned short*)(out_mean + (size_t)node * 128) + (c - 16) * 8;
      v = *(const uint4*)src;
    }
    *(uint4*)(As + row * 264 + c * 8) = v;
  }
  __syncthreads();

  const int mrow = (w & 3) * 32;
  const int ncol = (w >> 2) * 64;

  f32x4 acc[2][4];
#pragma unroll
  for (int i = 0; i < 2; ++i)
#pragma unroll
    for (int j = 0; j < 4; ++j) acc[i][j] = (f32x4)(0.0f);

#pragma unroll
  for (int kk = 0; kk < 8; ++kk) {
    int ko = kk * 32 + q * 8;
    bf16x8 a0 = *(const bf16x8*)(As + (mrow + s) * 264 + ko);
    bf16x8 a1 = *(const bf16x8*)(As + (mrow + 16 + s) * 264 + ko);
    bf16x8 bv[4];
#pragma unroll
    for (int j = 0; j < 4; ++j)
      bv[j] = *(const bf16x8*)(Bs + (ncol + j * 16 + s) * 264 + ko);
#pragma unroll
    for (int j = 0; j < 4; ++j) {
      acc[0][j] = __builtin_amdgcn_mfma_f32_16x16x32_bf16(a0, bv[j], acc[0][j], 0, 0, 0);
      acc[1][j] = __builtin_amdgcn_mfma_f32_16x16x32_bf16(a1, bv[j], acc[1][j], 0, 0, 0);
    }
  }
  __syncthreads();

  float* hS = (float*)As;  // [128][132]
#pragma unroll
  for (int i = 0; i < 2; ++i)
#pragma unroll
    for (int j = 0; j < 4; ++j)
#pragma unroll
      for (int r = 0; r < 4; ++r) {
        int row = mrow + i * 16 + q * 4 + r;
        int col = ncol + j * 16 + s;
        float h = acc[i][j][r] + bias_s[col];
        hS[row * 132 + col] = fmaxf(h, 0.0f);
      }
  __syncthreads();

  float gx = gamma[2 * lane], gy = gamma[2 * lane + 1];
  float bx = beta[2 * lane],  by = beta[2 * lane + 1];
#pragma unroll 4
  for (int rr = 0; rr < 16; ++rr) {
    int row = w * 16 + rr;
    int node = base + row;
    float v0 = hS[row * 132 + 2 * lane];
    float v1 = hS[row * 132 + 2 * lane + 1];
    float s1 = v0 + v1, s2 = v0 * v0 + v1 * v1;
#pragma unroll
    for (int m = 1; m < 64; m <<= 1) {
      s1 += __shfl_xor(s1, m, 64);
      s2 += __shfl_xor(s2, m, 64);
    }
    float mu = s1 * (1.0f / 128.0f);
    float var = s2 * (1.0f / 128.0f) - mu * mu;
    float rstd = rsqrtf(var + LN_EPS);
    if (node < N_NODES) {
      float2 o;
      o.x = (v0 - mu) * rstd * gx + bx;
      o.y = (v1 - mu) * rstd * gy + by;
      *(float2*)(out + (size_t)node * 128 + 2 * lane) = o;
    }
  }
}

extern "C" void kernel_launch(void* const* d_in, const int* in_sizes, int n_in,
                              void* d_out, int out_size, void* d_ws, size_t ws_size,
                              hipStream_t stream) {
  const float* x     = (const float*)d_in[0];
  const int*   ei    = (const int*)d_in[1];
  const float* Wagg  = (const float*)d_in[2];
  const float* bagg  = (const float*)d_in[3];
  const float* Wself = (const float*)d_in[4];
  const float* bself = (const float*)d_in[5];
  const float* gamma = (const float*)d_in[6];
  const float* beta  = (const float*)d_in[7];
  float* out = (float*)d_out;

  // ws: xb | xf8 | wcat | bsum | hist | partials | scanned | edges_part (~46 MB)
  unsigned short* xb   = (unsigned short*)d_ws;            // 25.6 MB
  unsigned* xf8    = (unsigned*)(xb + (size_t)N_NODES * D); // 12.8 MB (32 u32/row)
  unsigned short* wcat = (unsigned short*)(xf8 + (size_t)N_NODES * 32); // 64 KB
  float* bsum      = (float*)(wcat + 128 * 256);           // 512 B
  int* hist        = (int*)(bsum + 128);                   // M_HIST ints
  int* partials    = hist + M_HIST;                        // NPART (pad 1280)
  int* scanned     = partials + 1280;                      // M_HIST ints
  unsigned* edges_part = (unsigned*)(scanned + M_HIST);    // N_EDGES (6.4 MB)

  prep_kernel<<<NBLK + XCB + 16, 256, 0, stream>>>(
      x, ei, Wself, Wagg, bself, bagg, xb, xf8, wcat, bsum, hist);

  scan_partials<<<NPART, 256, 0, stream>>>(hist, partials);
  scan_block<<<1, 256, 0, stream>>>(partials);
  scan_final<<<NPART, 256, 0, stream>>>(hist, partials, scanned);
  partB_scatter<<<NBLK, 256, 0, stream>>>(ei, scanned, edges_part);

  aggregate_bucket<<<NBUCKET, 256, 0, stream>>>(xf8, scanned, edges_part, out);

  gemm_mfma_ln<<<(N_NODES + 127) / 128, 512, 0, stream>>>(
      xb, out, wcat, bsum, gamma, beta, out);
}

// Round 8
// 239.285 us; speedup vs baseline: 1.1936x; 1.1936x over previous
//
#include <hip/hip_runtime.h>

#define N_NODES 100000
#define N_EDGES 1600000
#define D 128
#define RPB 64                        // node rows per bucket
#define NBUCKET 1563                  // ceil(N_NODES / RPB)
#define NBLK 196                      // edge chunks
#define EPB 8192                      // edges per chunk
#define CHO 1564                      // chunkoff row stride (NBUCKET offsets + end)
#define AGG_CAP 2048                  // max edges per bucket (mean 1024, +32 sigma)
#define XCB 3125                      // xconv blocks (3.2M float4 / 1024)
#define SCAN_PAD 1792                 // 256*7 >= NBUCKET

constexpr float LN_EPS   = 1e-5f;
constexpr float MEAN_EPS = 1e-8f;

typedef __attribute__((ext_vector_type(8))) short bf16x8;
typedef __attribute__((ext_vector_type(4))) float f32x4;

__device__ inline float bf2f(unsigned short h) {
  union { unsigned u; float f; } v; v.u = (unsigned)h << 16; return v.f;
}
__device__ inline unsigned short f2bf(float f) {
  union { float f; unsigned u; } v; v.f = f;
  return (unsigned short)((v.u + 0x7FFFu + ((v.u >> 16) & 1u)) >> 16);
}

// ---------------------------------------------------------------------------
// Fused prep: blocks [0,NBLK) = per-chunk bucket sort (hist -> local scan ->
// LDS scatter -> dense coalesced write + chunkoff). [NBLK,NBLK+XCB) = x->bf16.
// Last 16 = W concat + bias. No global scan, no device-wide atomics.
// ---------------------------------------------------------------------------
__global__ __launch_bounds__(256) void prep_sort(
    const float* __restrict__ x, const int* __restrict__ ei,
    const float* __restrict__ Wself, const float* __restrict__ Wagg,
    const float* __restrict__ bself, const float* __restrict__ bagg,
    unsigned short* __restrict__ xb, unsigned short* __restrict__ wcat,
    float* __restrict__ bsum, unsigned* __restrict__ ent_sorted,
    int* __restrict__ chunkoff) {
  __shared__ int ent_s[EPB];        // 32 KB
  __shared__ int cnt_s[SCAN_PAD];   // 7 KB
  __shared__ int off_s[SCAN_PAD];   // 7 KB (becomes cursors after chunkoff write)
  __shared__ int sb[256];
  const int bid = blockIdx.x;
  const int t = threadIdx.x;

  if (bid < NBLK) {
    const int ebase = bid * EPB;
    const int nch = min(EPB, N_EDGES - ebase);       // last chunk: 2560
    const int base4 = bid * (EPB / 4);
    const int end4 = base4 + (nch >> 2);             // nch divisible by 4

    for (int i = t; i < SCAN_PAD; i += 256) cnt_s[i] = 0;
    __syncthreads();

    // pass 1: histogram
#pragma unroll
    for (int k = 0; k < EPB / 1024; ++k) {
      int i4 = base4 + k * 256 + t;
      if (i4 < end4) {
        int4 r = ((const int4*)ei)[i4];
        atomicAdd(&cnt_s[r.x >> 6], 1);
        atomicAdd(&cnt_s[r.y >> 6], 1);
        atomicAdd(&cnt_s[r.z >> 6], 1);
        atomicAdd(&cnt_s[r.w >> 6], 1);
      }
    }
    __syncthreads();

    // blocked exclusive scan over SCAN_PAD (=256*7) entries
    int psum = 0;
#pragma unroll
    for (int i = 0; i < 7; ++i) psum += cnt_s[t * 7 + i];
    sb[t] = psum;
    __syncthreads();
    for (int off = 1; off < 256; off <<= 1) {
      int u = (t >= off) ? sb[t - off] : 0;
      __syncthreads();
      sb[t] += u;
      __syncthreads();
    }
    int run = sb[t] - psum;
#pragma unroll
    for (int i = 0; i < 7; ++i) {
      off_s[t * 7 + i] = run;
      run += cnt_s[t * 7 + i];
    }
    __syncthreads();

    // write chunkoff BEFORE scatter destroys off_s
    for (int b = t; b < NBUCKET; b += 256)
      chunkoff[bid * CHO + b] = off_s[b];
    if (t == 0) chunkoff[bid * CHO + NBUCKET] = nch;
    __syncthreads();

    // pass 2: LDS scatter into bucket-sorted order (off_s as cursors)
#pragma unroll
    for (int k = 0; k < EPB / 1024; ++k) {
      int i4 = base4 + k * 256 + t;
      if (i4 < end4) {
        int4 r = ((const int4*)ei)[i4];
        int4 c = ((const int4*)(ei + N_EDGES))[i4];
        int p0 = atomicAdd(&off_s[r.x >> 6], 1);
        ent_s[p0] = ((r.x & 63) << 17) | c.x;
        int p1 = atomicAdd(&off_s[r.y >> 6], 1);
        ent_s[p1] = ((r.y & 63) << 17) | c.y;
        int p2 = atomicAdd(&off_s[r.z >> 6], 1);
        ent_s[p2] = ((r.z & 63) << 17) | c.z;
        int p3 = atomicAdd(&off_s[r.w >> 6], 1);
        ent_s[p3] = ((r.w & 63) << 17) | c.w;
      }
    }
    __syncthreads();

    // dense coalesced write-out
    for (int i = t; i < nch; i += 256)
      ent_sorted[ebase + i] = (unsigned)ent_s[i];
  } else if (bid < NBLK + XCB) {
    // ---- xconv: 4 float4 per thread -> bf16x4
    const int base = (bid - NBLK) * 1024;
#pragma unroll
    for (int k = 0; k < 4; ++k) {
      int i4 = base + k * 256 + t;   // XCB*1024 == 3.2M exact
      float4 v = ((const float4*)x)[i4];
      ushort4 o;
      o.x = f2bf(v.x); o.y = f2bf(v.y); o.z = f2bf(v.z); o.w = f2bf(v.w);
      ((ushort4*)xb)[i4] = o;
    }
  } else {
    // ---- wconv: 16 blocks cover 128x256 weights
    const int blk = bid - NBLK - XCB;
#pragma unroll
    for (int k = 0; k < 8; ++k) {
      int idx = blk * 2048 + k * 256 + t;
      int o = idx >> 8, kc = idx & 255;
      float v = (kc < 128) ? Wself[o * 128 + kc] : Wagg[o * 128 + (kc - 128)];
      wcat[o * 256 + kc] = f2bf(v);
    }
    if (blk == 0 && t < 128) bsum[t] = bself[t] + bagg[t];
  }
}

// ---------------------------------------------------------------------------
// Aggregate: block b collects its bucket's entries from 196 contiguous
// chunk slices (196-length scan + parallel slice copy), row counting sort
// in LDS, then R5's proven bf16 gather loop. Mean written bf16 into the
// first 256B of the node's d_out row (overwritten later by the gemm).
// ---------------------------------------------------------------------------
__global__ __launch_bounds__(256) void aggregate(
    const unsigned short* __restrict__ xb, const unsigned* __restrict__ ent_sorted,
    const int* __restrict__ chunkoff, float* out) {
  __shared__ int ent_s[AGG_CAP];   // 8 KB
  __shared__ int col_s[AGG_CAP];   // 8 KB
  __shared__ int sb[256];
  __shared__ int cnt_s[RPB];
  __shared__ int off_s[RPB];
  __shared__ int cur_s[RPB];

  const int b = blockIdx.x;
  const int t = threadIdx.x;

  // slice info + scan of lengths
  int beg = 0, len = 0;
  if (t < NBLK) {
    beg = chunkoff[t * CHO + b];
    len = chunkoff[t * CHO + b + 1] - beg;
  }
  sb[t] = len;
  __syncthreads();
  for (int off = 1; off < 256; off <<= 1) {
    int u = (t >= off) ? sb[t - off] : 0;
    __syncthreads();
    sb[t] += u;
    __syncthreads();
  }
  int n = sb[255]; if (n > AGG_CAP) n = AGG_CAP;
  int dst = sb[t] - len;
  // parallel slice copy (196 threads, ~5 entries each, contiguous reads)
  if (t < NBLK) {
    const unsigned* src = ent_sorted + t * EPB + beg;
    for (int i = 0; i < len; ++i)
      if (dst + i < AGG_CAP) ent_s[dst + i] = (int)src[i];
  }
  __syncthreads();

  // row counting sort
  if (t < RPB) cnt_s[t] = 0;
  __syncthreads();
  for (int i = t; i < n; i += 256) atomicAdd(&cnt_s[ent_s[i] >> 17], 1);
  __syncthreads();
  if (t < RPB) off_s[t] = cnt_s[t];
  __syncthreads();
  for (int off = 1; off < RPB; off <<= 1) {
    int u = 0;
    if (t < RPB && t >= off) u = off_s[t - off];
    __syncthreads();
    if (t < RPB) off_s[t] += u;
    __syncthreads();
  }
  int excl = 0;
  if (t < RPB) excl = off_s[t] - cnt_s[t];
  __syncthreads();
  if (t < RPB) { off_s[t] = excl; cur_s[t] = excl; }
  __syncthreads();
  for (int i = t; i < n; i += 256) {
    int e = ent_s[i];
    int pos = atomicAdd(&cur_s[e >> 17], 1);
    col_s[pos] = e & 0x1FFFF;
  }
  __syncthreads();

  // gather: wave w -> rows w,w+4,...; 4 lane-groups x 16 lanes x uint4 (8 bf16)
  const int w = t >> 6, lane = t & 63;
  const int grp = lane >> 4, l = lane & 15;
  const int nodebase = b << 6;
  for (int lrow = w; lrow < RPB; lrow += 4) {
    int node = nodebase + lrow;
    if (node >= N_NODES) break;
    int rbeg = off_s[lrow];
    int deg = cnt_s[lrow];
    float acc[8];
#pragma unroll
    for (int k = 0; k < 8; ++k) acc[k] = 0.f;
    for (int j0 = 0; j0 < deg; j0 += 4) {
      int jj = j0 + grp;
      if (jj < deg) {
        int col = col_s[rbeg + jj];
        uint4 p = *(const uint4*)(xb + (size_t)col * D + l * 8);
        acc[0] += bf2f((unsigned short)(p.x & 0xFFFFu));
        acc[1] += bf2f((unsigned short)(p.x >> 16));
        acc[2] += bf2f((unsigned short)(p.y & 0xFFFFu));
        acc[3] += bf2f((unsigned short)(p.y >> 16));
        acc[4] += bf2f((unsigned short)(p.z & 0xFFFFu));
        acc[5] += bf2f((unsigned short)(p.z >> 16));
        acc[6] += bf2f((unsigned short)(p.w & 0xFFFFu));
        acc[7] += bf2f((unsigned short)(p.w >> 16));
      }
    }
#pragma unroll
    for (int k = 0; k < 8; ++k) {
      acc[k] += __shfl_xor(acc[k], 16, 64);
      acc[k] += __shfl_xor(acc[k], 32, 64);
    }
    if (grp == 0) {
      float inv = 1.0f / ((float)deg + MEAN_EPS);
      uint4 o;
      o.x = (unsigned)f2bf(acc[0] * inv) | ((unsigned)f2bf(acc[1] * inv) << 16);
      o.y = (unsigned)f2bf(acc[2] * inv) | ((unsigned)f2bf(acc[3] * inv) << 16);
      o.z = (unsigned)f2bf(acc[4] * inv) | ((unsigned)f2bf(acc[5] * inv) << 16);
      o.w = (unsigned)f2bf(acc[6] * inv) | ((unsigned)f2bf(acc[7] * inv) << 16);
      ((uint4*)(out + (size_t)node * D))[l] = o;
    }
  }
}

// ---------------------------------------------------------------------------
// MFMA GEMM: C[100000x128] = [x_bf16 | mean_bf16] (K=256) @ Wcat^T  + LN
// (unchanged from R3-R6)
// ---------------------------------------------------------------------------
__global__ __launch_bounds__(512) void gemm_mfma_ln(
    const unsigned short* __restrict__ xb, const float* out_mean,
    const unsigned short* __restrict__ wcat, const float* __restrict__ bsum,
    const float* __restrict__ gamma, const float* __restrict__ beta,
    float* out) {
  __shared__ unsigned short As[128 * 264];
  __shared__ unsigned short Bs[128 * 264];
  __shared__ float bias_s[128];

  const int t = threadIdx.x;
  const int w = t >> 6, lane = t & 63;
  const int q = lane >> 4, s = lane & 15;
  const int base = blockIdx.x * 128;

  if (t < 128) bias_s[t] = bsum[t];

#pragma unroll
  for (int r = 0; r < 8; ++r) {
    int f = r * 512 + t;
    int row = f >> 5, c = f & 31;
    uint4 v = *(const uint4*)(wcat + row * 256 + c * 8);
    *(uint4*)(Bs + row * 264 + c * 8) = v;
  }
#pragma unroll
  for (int r = 0; r < 8; ++r) {
    int f = r * 512 + t;
    int row = f >> 5, c = f & 31;
    int node = base + row;
    uint4 v = make_uint4(0, 0, 0, 0);
    if (node < N_NODES) {
      const unsigned short* src = (c < 16)
          ? xb + (size_t)node * 128 + c * 8
          : (const unsigned short*)(out_mean + (size_t)node * 128) + (c - 16) * 8;
      v = *(const uint4*)src;
    }
    *(uint4*)(As + row * 264 + c * 8) = v;
  }
  __syncthreads();

  const int mrow = (w & 3) * 32;
  const int ncol = (w >> 2) * 64;

  f32x4 acc[2][4];
#pragma unroll
  for (int i = 0; i < 2; ++i)
#pragma unroll
    for (int j = 0; j < 4; ++j) acc[i][j] = (f32x4)(0.0f);

#pragma unroll
  for (int kk = 0; kk < 8; ++kk) {
    int ko = kk * 32 + q * 8;
    bf16x8 a0 = *(const bf16x8*)(As + (mrow + s) * 264 + ko);
    bf16x8 a1 = *(const bf16x8*)(As + (mrow + 16 + s) * 264 + ko);
    bf16x8 bv[4];
#pragma unroll
    for (int j = 0; j < 4; ++j)
      bv[j] = *(const bf16x8*)(Bs + (ncol + j * 16 + s) * 264 + ko);
#pragma unroll
    for (int j = 0; j < 4; ++j) {
      acc[0][j] = __builtin_amdgcn_mfma_f32_16x16x32_bf16(a0, bv[j], acc[0][j], 0, 0, 0);
      acc[1][j] = __builtin_amdgcn_mfma_f32_16x16x32_bf16(a1, bv[j], acc[1][j], 0, 0, 0);
    }
  }
  __syncthreads();

  float* hS = (float*)As;  // [128][132]
#pragma unroll
  for (int i = 0; i < 2; ++i)
#pragma unroll
    for (int j = 0; j < 4; ++j)
#pragma unroll
      for (int r = 0; r < 4; ++r) {
        int row = mrow + i * 16 + q * 4 + r;
        int col = ncol + j * 16 + s;
        float h = acc[i][j][r] + bias_s[col];
        hS[row * 132 + col] = fmaxf(h, 0.0f);
      }
  __syncthreads();

  float gx = gamma[2 * lane], gy = gamma[2 * lane + 1];
  float bx = beta[2 * lane],  by = beta[2 * lane + 1];
#pragma unroll 4
  for (int rr = 0; rr < 16; ++rr) {
    int row = w * 16 + rr;
    int node = base + row;
    float v0 = hS[row * 132 + 2 * lane];
    float v1 = hS[row * 132 + 2 * lane + 1];
    float s1 = v0 + v1, s2 = v0 * v0 + v1 * v1;
#pragma unroll
    for (int m = 1; m < 64; m <<= 1) {
      s1 += __shfl_xor(s1, m, 64);
      s2 += __shfl_xor(s2, m, 64);
    }
    float mu = s1 * (1.0f / 128.0f);
    float var = s2 * (1.0f / 128.0f) - mu * mu;
    float rstd = rsqrtf(var + LN_EPS);
    if (node < N_NODES) {
      float2 o;
      o.x = (v0 - mu) * rstd * gx + bx;
      o.y = (v1 - mu) * rstd * gy + by;
      *(float2*)(out + (size_t)node * 128 + 2 * lane) = o;
    }
  }
}

extern "C" void kernel_launch(void* const* d_in, const int* in_sizes, int n_in,
                              void* d_out, int out_size, void* d_ws, size_t ws_size,
                              hipStream_t stream) {
  const float* x     = (const float*)d_in[0];
  const int*   ei    = (const int*)d_in[1];
  const float* Wagg  = (const float*)d_in[2];
  const float* bagg  = (const float*)d_in[3];
  const float* Wself = (const float*)d_in[4];
  const float* bself = (const float*)d_in[5];
  const float* gamma = (const float*)d_in[6];
  const float* beta  = (const float*)d_in[7];
  float* out = (float*)d_out;

  // ws: xb | wcat | bsum | ent_sorted | chunkoff   (~33.3 MB)
  unsigned short* xb   = (unsigned short*)d_ws;                 // 25.6 MB
  unsigned short* wcat = xb + (size_t)N_NODES * D;              // 64 KB
  float* bsum      = (float*)(wcat + 128 * 256);                // 512 B
  unsigned* ent_sorted = (unsigned*)(bsum + 128);               // NBLK*EPB u32 (6.4 MB)
  int* chunkoff    = (int*)(ent_sorted + (size_t)NBLK * EPB);   // NBLK*CHO (1.23 MB)

  prep_sort<<<NBLK + XCB + 16, 256, 0, stream>>>(
      x, ei, Wself, Wagg, bself, bagg, xb, wcat, bsum, ent_sorted, chunkoff);

  aggregate<<<NBUCKET, 256, 0, stream>>>(xb, ent_sorted, chunkoff, out);

  gemm_mfma_ln<<<(N_NODES + 127) / 128, 512, 0, stream>>>(
      xb, out, wcat, bsum, gamma, beta, out);
}